// Round 14
// baseline (142.915 us; speedup 1.0000x reference)
//
#include <hip/hip_runtime.h>

// AdaptiveSparsityAttention on MI355X (gfx950).
// f32 in/out, internal bf16 MFMA; mask logits in pure f32 via algebraic
// fusion:  a = x @ (0.5*(Wq[:,:256]+Wq[:,256:]) @ W1[:256]) + b1.
//
// R14 (base = R12/R13 @100.3us): k_scores RESTRUCTURED — mask VALU work
//   interleaved INTO the QK^T k-loop (stage gloads -> 4 mask h4-iters hide
//   the load latency -> barrier -> ds_read+MFMA). Single-buffer GEMM LDS;
//   a,c read global-direct (L2-hot broadcast). LDS 21KB. Kills the R13
//   convoy (mask phase then mem phase serial = 43.5us @ VALUBusy 40%).
// 5 launches: prep, qkvac, scores, pv, out.

typedef unsigned short u16t;
typedef __bf16 bf16x8 __attribute__((ext_vector_type(8)));
typedef float f32x4 __attribute__((ext_vector_type(4)));

#define B_SZ 2
#define S_SZ 1024
#define D_SZ 512
#define DH 256
#define HH 128   // hidden dim of sparsity predictor

static __device__ __forceinline__ u16t f2b(float f) {
    unsigned int u = __builtin_bit_cast(unsigned int, f);
    u += 0x7FFFu + ((u >> 16) & 1u);
    return (u16t)(u >> 16);
}

static __device__ __forceinline__ f32x4 mfma16(bf16x8 a, bf16x8 b, f32x4 c) {
    return __builtin_amdgcn_mfma_f32_16x16x32_bf16(a, b, c, 0, 0, 0);
}

static __device__ __forceinline__ void gload16(const void* g, void* l) {
    __builtin_amdgcn_global_load_lds(
        (const __attribute__((address_space(1))) void*)g,
        (__attribute__((address_space(3))) void*)l, 16, 0, 0);
}

// ---------------------------------------------------------- K0: fused prep
// blocks [0,1024): x->bf16 | [1024,2048): W transposes | [2048,2560): Beff
__global__ __launch_bounds__(256) void k_prep(
    const float* __restrict__ x,
    const float* __restrict__ Wq, const float* __restrict__ Wk,
    const float* __restrict__ Wv, const float* __restrict__ Wo,
    const float* __restrict__ W1,
    u16t* __restrict__ xb, u16t* __restrict__ WT, float* __restrict__ Beff)
{
    __shared__ float smf[1088];   // union: tile[32][33] (trans) | wm[2][256] (eff)
    int bidx = blockIdx.x;
    int t = threadIdx.x;
    if (bidx < 1024) {
        int idx = (bidx * 256 + t) * 4;
        float4 v = *(const float4*)(x + idx);
        u16t* o = xb + idx;
        o[0] = f2b(v.x); o[1] = f2b(v.y); o[2] = f2b(v.z); o[3] = f2b(v.w);
    } else if (bidx < 2048) {
        int t2 = bidx - 1024;
        int z = t2 >> 8, rem = t2 & 255;
        int n0 = (rem & 15) * 32, k0 = (rem >> 4) * 32;
        const float* W = z == 0 ? Wq : z == 1 ? Wk : z == 2 ? Wv : Wo;
        u16t* WTz = WT + (size_t)z * D_SZ * D_SZ;
        float (*tile)[33] = (float(*)[33])smf;
        int r = t >> 3, c4 = (t & 7) * 4;
        float4 v = *(const float4*)(W + (size_t)(k0 + r) * D_SZ + n0 + c4);
        tile[r][c4] = v.x; tile[r][c4 + 1] = v.y; tile[r][c4 + 2] = v.z; tile[r][c4 + 3] = v.w;
        __syncthreads();
        u16t o[4];
        o[0] = f2b(tile[c4][r]); o[1] = f2b(tile[c4 + 1][r]);
        o[2] = f2b(tile[c4 + 2][r]); o[3] = f2b(tile[c4 + 3][r]);
        *(ushort4*)(WTz + (size_t)(n0 + r) * D_SZ + k0 + c4) = *(ushort4*)o;
    } else {
        int k = bidx - 2048;   // 0..511
        float* wm0 = smf;
        float* wm1 = smf + 256;
        const float* wrq = Wq + (size_t)k * D_SZ;
        const float* wrk = Wk + (size_t)k * D_SZ;
        wm0[t & 255] = 0.5f * (wrq[t & 255] + wrq[(t & 255) + DH]);
        wm1[t & 255] = 0.5f * (wrk[t & 255] + wrk[(t & 255) + DH]);
        __syncthreads();
        int half = t >> 7, hcol = t & 127;
        const float* wm = half ? wm1 : wm0;
        const float* W1h = W1 + (half ? (size_t)DH * HH : 0);
        float s = 0.f;
        for (int d = 0; d < 256; ++d) s += wm[d] * W1h[(size_t)d * HH + hcol];
        Beff[(size_t)k * 256 + half * 128 + hcol] = s;
    }
}

// ---------------------------- 2-phase double-buffered GEMM mainloop (swizzled)
// C[BM=MF*64][BN=NF*16] per block (256 thr, 4 waves; wave w owns MF*16 rows).
// LDS physical slot p of row r holds logical 16B-slot p^(r&7): staged by
// swizzling the GLOBAL source column; frag reads use slot (kk*4+kg)^(r&7).
template<int MF, int NF>
static __device__ __forceinline__ void gemm_db(
    const u16t* __restrict__ A, int lda, const u16t* __restrict__ B, int ldb,
    int K, int tid, u16t* Als, u16t* Bls, f32x4 acc[MF][NF])
{
    const int w = tid >> 6, lane = tid & 63;
    const int lr = lane & 15, kg = lane >> 4;
    const int srow = lane >> 3;
    const int scol = ((lane & 7) ^ srow) * 8;   // swizzled global col (u16)
    const int ABUF = MF * 4096;   // u16 elems per A buffer
    const int BBUF = NF * 1024;   // u16 elems per B buffer
    auto stage = [&](int bb, int k0) {
#pragma unroll
        for (int q = 0; q < MF * 2; ++q) {
            int ci = w * (MF * 2) + q;
            gload16(A + (size_t)(ci * 8 + srow) * lda + k0 + scol,
                    Als + bb * ABUF + ci * 512);
        }
#pragma unroll
        for (int q = 0; q < NF / 2; ++q) {
            int cj = w * (NF / 2) + q;
            gload16(B + (size_t)(cj * 8 + srow) * ldb + k0 + scol,
                    Bls + bb * BBUF + cj * 512);
        }
    };
    stage(0, 0);
    __syncthreads();
    const int nt = K / 64;
    for (int t = 0; t < nt; ++t) {
        int cur = t & 1;
        if (t + 1 < nt) stage(cur ^ 1, (t + 1) * 64);
        const u16t* Ab = Als + cur * ABUF;
        const u16t* Bb = Bls + cur * BBUF;
#pragma unroll
        for (int kk = 0; kk < 2; ++kk) {
            bf16x8 af[MF], bfr[NF];
#pragma unroll
            for (int fi = 0; fi < MF; ++fi) {
                int r = w * (MF * 16) + fi * 16 + lr;
                af[fi] = *(const bf16x8*)(&Ab[r * 64 + (((kk * 4 + kg) ^ (r & 7)) << 3)]);
            }
#pragma unroll
            for (int fj = 0; fj < NF; ++fj) {
                int r = fj * 16 + lr;
                bfr[fj] = *(const bf16x8*)(&Bb[r * 64 + (((kk * 4 + kg) ^ (r & 7)) << 3)]);
            }
#pragma unroll
            for (int fi = 0; fi < MF; ++fi)
#pragma unroll
                for (int fj = 0; fj < NF; ++fj)
                    acc[fi][fj] = mfma16(af[fi], bfr[fj], acc[fi][fj]);
        }
        __syncthreads();
    }
}

// C-frag (fi,fj,rr): row = m0+w*MF*16+fi*16+kg*4+rr, col = n0+fj*16+lr  [m89]

// ------------------------------------------- K1: fused QKV GEMMs + mask-ac GEMM
// 1D grid, 640 blocks: [0,384) -> qkv (z = bid/128, MF=2); [384,640) -> ac.
__global__ __launch_bounds__(256) void k_qkvac(
    const u16t* __restrict__ xb, const u16t* __restrict__ WT,
    const float* __restrict__ x, const float* __restrict__ Beff,
    const float* __restrict__ b1,
    u16t* __restrict__ qb, u16t* __restrict__ kb, u16t* __restrict__ vT,
    float* __restrict__ a, float* __restrict__ cc)
{
    __shared__ __align__(16) char sm[49152];   // qkv: A 2x16KB + B 2x8KB = 48KB
    int bid = blockIdx.x;
    int t = threadIdx.x;
    if (bid < 384) {
        u16t* Als = (u16t*)sm;
        u16t* Bls = (u16t*)(sm + 32768);
        int z = bid / 128, rem = bid & 127;
        int m0 = (rem >> 3) * 128, n0 = (rem & 7) * 64;
        const u16t* A = xb + (size_t)m0 * D_SZ;
        const u16t* Bt = WT + (size_t)z * D_SZ * D_SZ + (size_t)n0 * D_SZ;
        f32x4 acc[2][4] = {};
        gemm_db<2, 4>(A, D_SZ, Bt, D_SZ, D_SZ, t, Als, Bls, acc);
        int w = t >> 6, lane = t & 63, lr = lane & 15, kg = lane >> 4;
        if (z < 2) {
            u16t (*vls)[68] = (u16t(*)[68])sm;
            float scale = z == 0 ? 0.0625f : 1.0f;
#pragma unroll
            for (int fi = 0; fi < 2; ++fi)
#pragma unroll
                for (int fj = 0; fj < 4; ++fj)
#pragma unroll
                    for (int rr = 0; rr < 4; ++rr)
                        vls[w * 32 + fi * 16 + kg * 4 + rr][fj * 16 + lr]
                            = f2b(acc[fi][fj][rr] * scale);
            __syncthreads();
            u16t* dst = z == 0 ? qb : kb;
            int c8 = (t & 7) * 8, r0 = t >> 3;
#pragma unroll
            for (int p = 0; p < 4; ++p) {
                int r = r0 + p * 32;
                *(uint4*)(dst + (size_t)(m0 + r) * D_SZ + n0 + c8) = *(const uint4*)(&vls[r][c8]);
            }
        } else {
            u16t (*vls)[136] = (u16t(*)[136])sm;   // 64*136*2 = 17408
#pragma unroll
            for (int fi = 0; fi < 2; ++fi)
#pragma unroll
                for (int fj = 0; fj < 4; ++fj)
#pragma unroll
                    for (int rr = 0; rr < 4; ++rr)
                        vls[fj * 16 + lr][w * 32 + fi * 16 + kg * 4 + rr] = f2b(acc[fi][fj][rr]);
            __syncthreads();
            int b = m0 >> 10, s0 = m0 & 1023;
            int cr = t >> 2, seg = t & 3;
            const u16t* srcp = &vls[cr][seg * 32];
            u16t* dstp = vT + (((size_t)(b * D_SZ + n0 + cr)) << 10) + s0 + seg * 32;
#pragma unroll
            for (int qq = 0; qq < 4; ++qq)
                *(uint4*)(dstp + qq * 8) = *(const uint4*)(srcp + qq * 8);
        }
    } else {
        // [a|c] = x @ Beff (f32), a gets +b1. 64 rows x 32 cols, 4x2/thread.
        float (*xs)[68] = (float(*)[68])sm;            // 64x68
        float (*bsT)[68] = (float(*)[68])(sm + 17408); // 32x68 [n][k]
        int t2 = bid - 384;
        int r0 = (t2 & 31) * 64, n0 = (t2 >> 5) * 32;
        int ti = t >> 4, tj = t & 15;
        float acc[4][2] = {};
        for (int k0 = 0; k0 < 512; k0 += 64) {
            if (k0) __syncthreads();
#pragma unroll
            for (int p = 0; p < 4; ++p) {
                int idx = t + p * 256;
                int r = idx >> 4, c4 = (idx & 15) * 4;
                *(float4*)&xs[r][c4] = *(const float4*)(x + (size_t)(r0 + r) * D_SZ + k0 + c4);
            }
#pragma unroll
            for (int p = 0; p < 2; ++p) {
                int idx = t + p * 256;
                int k = idx >> 3, n4 = (idx & 7) * 4;
                float4 v = *(const float4*)(Beff + (size_t)(k0 + k) * 256 + n0 + n4);
                bsT[n4][k] = v.x; bsT[n4 + 1][k] = v.y; bsT[n4 + 2][k] = v.z; bsT[n4 + 3][k] = v.w;
            }
            __syncthreads();
#pragma unroll
            for (int kk = 0; kk < 16; ++kk) {
                float4 xv[4], bv[2];
#pragma unroll
                for (int ri = 0; ri < 4; ++ri) xv[ri] = *(const float4*)&xs[ti + 16 * ri][kk * 4];
#pragma unroll
                for (int rj = 0; rj < 2; ++rj) bv[rj] = *(const float4*)&bsT[tj + 16 * rj][kk * 4];
#pragma unroll
                for (int ri = 0; ri < 4; ++ri)
#pragma unroll
                    for (int rj = 0; rj < 2; ++rj)
                        acc[ri][rj] += xv[ri].x * bv[rj].x + xv[ri].y * bv[rj].y
                                     + xv[ri].z * bv[rj].z + xv[ri].w * bv[rj].w;
            }
        }
        bool isA = n0 < 128;
#pragma unroll
        for (int rj = 0; rj < 2; ++rj) {
            int col = n0 + tj + 16 * rj;
            float badd = isA ? b1[col] : 0.f;
#pragma unroll
            for (int ri = 0; ri < 4; ++ri) {
                int row = r0 + ti + 16 * ri;
                if (isA) a[(size_t)row * HH + col] = acc[ri][rj] + badd;
                else     cc[(size_t)row * HH + (col - 128)] = acc[ri][rj];
            }
        }
    }
}

// -------------- K2: scores with mask INTERLEAVED into the QK^T k-loop
// grid (16 jb, 16 mt, 2 b). Per k-chunk t8 (8 total): {issue gloads ->
// 4 mask h4-iters (a,c global-broadcast; hides load latency) -> barrier ->
// ds_read+MFMA (acc0 for h0 chunks 0-3, acc1 for h1 chunks 4-7) -> barrier}.
// Then msk bits -> LDS, exp+mask -> P + lpart per head.  LDS 21KB.
__global__ __launch_bounds__(256) void k_scores(
    const u16t* __restrict__ qb, const u16t* __restrict__ kb,
    const float* __restrict__ a, const float* __restrict__ c,
    const float* __restrict__ W2, const float* __restrict__ b2,
    u16t* __restrict__ P, float* __restrict__ lpart)
{
    __shared__ __align__(16) char sm[21504];
    u16t* Als = (u16t*)sm;              // 8KB single buffer
    u16t* Bls = (u16t*)(sm + 8192);     // 8KB single buffer
    unsigned char (*msk)[64] = (unsigned char(*)[64])(sm + 16384);  // 4KB
    float* w2s = (float*)(sm + 20480);  // 512B
    int b = blockIdx.z, mt = blockIdx.y, jb = blockIdx.x;
    int m0 = mt * 64, j0 = jb * 64;
    int t = threadIdx.x;
    if (t < 128) w2s[t] = W2[t];
    float fb2 = b2[0];
    int ti = t >> 4, tj = t & 15;
    const int w = t >> 6, lane = t & 63, lr = lane & 15, kg = lane >> 4;
    const int srow = lane >> 3;
    const int scol = ((lane & 7) ^ srow) * 8;   // swizzled global col (u16)
    const u16t* A = qb + (size_t)(b * S_SZ + m0) * D_SZ;
    const u16t* B = kb + (size_t)(b * S_SZ + j0) * D_SZ;
    // mask operand rows (global; 16-lane broadcast / L2-hot)
    const float* arow[4];
    const float* crow[4];
#pragma unroll
    for (int ri = 0; ri < 4; ++ri)
        arow[ri] = a + (size_t)(b * S_SZ + m0 + ti + 16 * ri) * HH;
#pragma unroll
    for (int rj = 0; rj < 4; ++rj)
        crow[rj] = c + (size_t)(b * S_SZ + j0 + tj + 16 * rj) * HH;
    float accm[4][4];
#pragma unroll
    for (int ri = 0; ri < 4; ++ri)
#pragma unroll
        for (int rj = 0; rj < 4; ++rj) accm[ri][rj] = fb2;
    f32x4 acc0[4] = {}, acc1[4] = {};
    __syncthreads();   // w2s visible before mask math
#pragma unroll
    for (int t8 = 0; t8 < 8; ++t8) {
        // issue this chunk's gloads (single buffer; prev reads done at barrier2)
#pragma unroll
        for (int q = 0; q < 2; ++q) {
            int ci = w * 2 + q;
            gload16(A + (size_t)(ci * 8 + srow) * D_SZ + t8 * 64 + scol, Als + ci * 512);
            gload16(B + (size_t)(ci * 8 + srow) * D_SZ + t8 * 64 + scol, Bls + ci * 512);
        }
        // mask chunk: 4 h4-iters under the gload latency
#pragma unroll
        for (int hh = 0; hh < 4; ++hh) {
            int h4 = t8 * 4 + hh;
            float4 wv = ((const float4*)w2s)[h4];
            float4 av[4], cv[4];
#pragma unroll
            for (int ri = 0; ri < 4; ++ri) av[ri] = ((const float4*)arow[ri])[h4];
#pragma unroll
            for (int rj = 0; rj < 4; ++rj) cv[rj] = ((const float4*)crow[rj])[h4];
#pragma unroll
            for (int ri = 0; ri < 4; ++ri)
#pragma unroll
                for (int rj = 0; rj < 4; ++rj) {
                    accm[ri][rj] += fmaxf(av[ri].x + cv[rj].x, 0.f) * wv.x;
                    accm[ri][rj] += fmaxf(av[ri].y + cv[rj].y, 0.f) * wv.y;
                    accm[ri][rj] += fmaxf(av[ri].z + cv[rj].z, 0.f) * wv.z;
                    accm[ri][rj] += fmaxf(av[ri].w + cv[rj].w, 0.f) * wv.w;
                }
        }
        __syncthreads();   // drains gloads (vmcnt0) + sync
        // ds_read + MFMA for this chunk
#pragma unroll
        for (int kk = 0; kk < 2; ++kk) {
            int ra = w * 16 + lr;
            bf16x8 af = *(const bf16x8*)(&Als[ra * 64 + (((kk * 4 + kg) ^ (ra & 7)) << 3)]);
            bf16x8 bfr[4];
#pragma unroll
            for (int fj = 0; fj < 4; ++fj) {
                int rb = fj * 16 + lr;
                bfr[fj] = *(const bf16x8*)(&Bls[rb * 64 + (((kk * 4 + kg) ^ (rb & 7)) << 3)]);
            }
            if (t8 < 4) {
#pragma unroll
                for (int fj = 0; fj < 4; ++fj) acc0[fj] = mfma16(af, bfr[fj], acc0[fj]);
            } else {
#pragma unroll
                for (int fj = 0; fj < 4; ++fj) acc1[fj] = mfma16(af, bfr[fj], acc1[fj]);
            }
        }
        __syncthreads();   // all reads of Als/Bls done before next overwrite
    }
    // publish mask bits
#pragma unroll
    for (int ri = 0; ri < 4; ++ri)
#pragma unroll
        for (int rj = 0; rj < 4; ++rj)
            msk[ti + 16 * ri][tj + 16 * rj] = accm[ri][rj] > 0.f ? 1 : 0;
    __syncthreads();
    // ---- exp + mask + lpart + P store, per head ----
    u16t (*vls)[68] = (u16t(*)[68])sm;   // 8704B, overlays Als/Bls
#pragma unroll
    for (int h = 0; h < 2; ++h) {
#pragma unroll
        for (int rr = 0; rr < 4; ++rr) {
            int il = w * 16 + kg * 4 + rr;
            float rs = 0.f;
#pragma unroll
            for (int fj = 0; fj < 4; ++fj) {
                int jl = fj * 16 + lr;
                float s = h ? acc1[fj][rr] : acc0[fj][rr];
                float e = msk[il][jl] ? __expf(s) : 0.f;
                if (h) acc1[fj][rr] = e; else acc0[fj][rr] = e;
                rs += e;
            }
            rs += __shfl_xor(rs, 1); rs += __shfl_xor(rs, 2);
            rs += __shfl_xor(rs, 4); rs += __shfl_xor(rs, 8);
            if (lr == 0)
                lpart[((size_t)(jb * 4 + b * 2 + h) << 10) + m0 + il] = rs;
        }
#pragma unroll
        for (int fj = 0; fj < 4; ++fj)
#pragma unroll
            for (int rr = 0; rr < 4; ++rr)
                vls[w * 16 + kg * 4 + rr][fj * 16 + lr]
                    = f2b(h ? acc1[fj][rr] : acc0[fj][rr]);
        __syncthreads();
        int r = t >> 2, c16 = (t & 3) * 16;
        u16t* dstp = P + ((size_t)(b * 2 + h) << 20) + ((size_t)(m0 + r) << 10) + j0 + c16;
        *(uint4*)dstp = *(const uint4*)(&vls[r][c16]);
        *(uint4*)(dstp + 8) = *(const uint4*)(&vls[r][c16 + 8]);
        __syncthreads();
    }
}

// ----------------------------- K3: PV (+ diag(1/l) epilogue), BM=64
// grid (8,16,4): n0=x*32, m0=y*64.
__global__ __launch_bounds__(256) void k_pv(
    const u16t* __restrict__ P, const u16t* __restrict__ vT,
    const float* __restrict__ lpart, u16t* __restrict__ ao)
{
    __shared__ __align__(16) u16t sm[12288];   // A 2x8KB + B 2x4KB = 24KB
    __shared__ float invl[64];
    u16t* Als = sm;
    u16t* Bls = sm + 8192;
    int bh = blockIdx.z, b = bh >> 1, h = bh & 1;
    int m0 = blockIdx.y * 64, n0 = blockIdx.x * 32;
    int t = threadIdx.x;
    if (t < 64) {   // fixed-order row-sum over 16 j-block partials (deterministic)
        float l = 0.f;
        for (int jb = 0; jb < 16; ++jb)
            l += lpart[((size_t)(jb * 4 + bh) << 10) + m0 + t];
        invl[t] = l > 0.f ? 1.0f / l : 0.f;
    }
    const u16t* A = P + ((size_t)bh << 20) + (size_t)m0 * S_SZ;
    const u16t* Bt = vT + ((size_t)(b * D_SZ + h * DH + n0)) * S_SZ;
    f32x4 acc[1][2] = {};
    gemm_db<1, 2>(A, S_SZ, Bt, S_SZ, S_SZ, t, Als, Bls, acc);
    int w = t >> 6, lane = t & 63, lr = lane & 15, kg = lane >> 4;
    u16t (*ols)[40] = (u16t(*)[40])sm;   // 64x40 u16 = 5120B
#pragma unroll
    for (int fj = 0; fj < 2; ++fj)
#pragma unroll
        for (int rr = 0; rr < 4; ++rr) {
            int rl = w * 16 + kg * 4 + rr;
            ols[rl][fj * 16 + lr] = f2b(acc[0][fj][rr] * invl[rl]);
        }
    __syncthreads();
    int r = t >> 2, c8 = (t & 3) * 8;
    *(uint4*)(ao + ((size_t)(b * S_SZ + m0 + r)) * D_SZ + h * DH + n0 + c8)
        = *(const uint4*)(&ols[r][c8]);
}

// ------------------------------------------ K4: out = ao@Wo+bo, BM=64
// grid (16,32): n0=x*32, m0=y*64.
__global__ __launch_bounds__(256) void k_out(
    const u16t* __restrict__ ao, const u16t* __restrict__ WoT,
    const float* __restrict__ bo, float* __restrict__ out)
{
    __shared__ __align__(16) u16t sm[12288];   // A 2x8KB + B 2x4KB = 24KB
    u16t* Als = sm;
    u16t* Bls = sm + 8192;
    int m0 = blockIdx.y * 64, n0 = blockIdx.x * 32;
    const u16t* A = ao + (size_t)m0 * D_SZ;
    const u16t* Bt = WoT + (size_t)n0 * D_SZ;
    f32x4 acc[1][2] = {};
    gemm_db<1, 2>(A, D_SZ, Bt, D_SZ, D_SZ, threadIdx.x, Als, Bls, acc);
    int w = threadIdx.x >> 6, lane = threadIdx.x & 63, lr = lane & 15, kg = lane >> 4;
    float (*ols)[36] = (float(*)[36])sm;   // 64x36 f32 = 9216B
#pragma unroll
    for (int fj = 0; fj < 2; ++fj)
#pragma unroll
        for (int rr = 0; rr < 4; ++rr) {
            int rl = w * 16 + kg * 4 + rr;
            ols[rl][fj * 16 + lr] = acc[0][fj][rr] + bo[n0 + fj * 16 + lr];
        }
    __syncthreads();
    int r0 = threadIdx.x >> 3, c4 = (threadIdx.x & 7) * 4;
#pragma unroll
    for (int p = 0; p < 2; ++p) {
        int r = r0 + p * 32;
        *(float4*)(out + (size_t)(m0 + r) * D_SZ + n0 + c4) = *(const float4*)(&ols[r][c4]);
    }
}

// ---------------------------------------------------------------------- host
extern "C" void kernel_launch(void* const* d_in, const int* in_sizes, int n_in,
                              void* d_out, int out_size, void* d_ws, size_t ws_size,
                              hipStream_t stream)
{
    const float* x  = (const float*)d_in[0];
    const float* Wq = (const float*)d_in[1];
    const float* Wk = (const float*)d_in[2];
    const float* Wv = (const float*)d_in[3];
    const float* Wo = (const float*)d_in[4];
    const float* bo = (const float*)d_in[5];
    const float* W1 = (const float*)d_in[6];
    const float* b1 = (const float*)d_in[7];
    const float* W2 = (const float*)d_in[8];
    const float* b2 = (const float*)d_in[9];
    float* out = (float*)d_out;

    // workspace carve (all 256B-aligned)
    char* ws = (char*)d_ws;
    size_t off = 0;
    auto carve = [&](size_t bytes) { void* p = ws + off; off += (bytes + 255) & ~(size_t)255; return p; };
    u16t* xb   = (u16t*)carve((size_t)2048 * 512 * 2);
    u16t* WT   = (u16t*)carve((size_t)4 * 512 * 512 * 2);
    u16t* qb   = (u16t*)carve((size_t)2048 * 512 * 2);
    u16t* kb   = (u16t*)carve((size_t)2048 * 512 * 2);
    u16t* vT   = (u16t*)carve((size_t)2 * 512 * 1024 * 2);
    float* Beff = (float*)carve((size_t)512 * 256 * 4);
    float* a   = (float*)carve((size_t)2048 * 128 * 4);
    float* c   = (float*)carve((size_t)2048 * 128 * 4);
    u16t* P    = (u16t*)carve((size_t)4 * 1024 * 1024 * 2);
    float* lpart = (float*)carve((size_t)16 * 4 * 1024 * 4);
    u16t* ao   = (u16t*)carve((size_t)2048 * 512 * 2);
    (void)ws_size;

    k_prep<<<dim3(2560), dim3(256), 0, stream>>>(x, Wq, Wk, Wv, Wo, W1, xb, WT, Beff);
    k_qkvac<<<dim3(640), dim3(256), 0, stream>>>(xb, WT, x, Beff, b1, qb, kb, vT, a, c);
    k_scores<<<dim3(16, 16, 2), dim3(256), 0, stream>>>(qb, kb, a, c, W2, b2, P, lpart);
    k_pv<<<dim3(8, 16, 4), dim3(256), 0, stream>>>(P, vT, lpart, ao);
    k_out<<<dim3(16, 32), dim3(256), 0, stream>>>(ao, WT + (size_t)3 * 512 * 512, bo, out);
}

// Round 15
// 100.792 us; speedup vs baseline: 1.4179x; 1.4179x over previous
//
#include <hip/hip_runtime.h>

// AdaptiveSparsityAttention on MI355X (gfx950).
// f32 in/out, internal bf16 MFMA; mask logits in pure f32 via algebraic
// fusion:  a = x @ (0.5*(Wq[:,:256]+Wq[:,256:]) @ W1[:256]) + b1.
//
// R15 (base = R12 @100.3us): k_scores PHASE-STAGGER — half the blocks
//   ((jb^mt)&1) run QK^T GEMM first then mask, half run mask first then
//   GEMM (phases are independent; mask only consumed at exp). Co-resident
//   blocks land in complementary phases -> mask VALU overlaps the other
//   block's gload/barrier stalls (m114). Phase internals byte-identical
//   to R12 (best-measured); only order flips.
// 5 launches: prep, qkvac, scores, pv, out.

typedef unsigned short u16t;
typedef __bf16 bf16x8 __attribute__((ext_vector_type(8)));
typedef float f32x4 __attribute__((ext_vector_type(4)));

#define B_SZ 2
#define S_SZ 1024
#define D_SZ 512
#define DH 256
#define HH 128   // hidden dim of sparsity predictor

static __device__ __forceinline__ u16t f2b(float f) {
    unsigned int u = __builtin_bit_cast(unsigned int, f);
    u += 0x7FFFu + ((u >> 16) & 1u);
    return (u16t)(u >> 16);
}

static __device__ __forceinline__ f32x4 mfma16(bf16x8 a, bf16x8 b, f32x4 c) {
    return __builtin_amdgcn_mfma_f32_16x16x32_bf16(a, b, c, 0, 0, 0);
}

static __device__ __forceinline__ void gload16(const void* g, void* l) {
    __builtin_amdgcn_global_load_lds(
        (const __attribute__((address_space(1))) void*)g,
        (__attribute__((address_space(3))) void*)l, 16, 0, 0);
}

// ---------------------------------------------------------- K0: fused prep
// blocks [0,1024): x->bf16 | [1024,2048): W transposes | [2048,2560): Beff
__global__ __launch_bounds__(256) void k_prep(
    const float* __restrict__ x,
    const float* __restrict__ Wq, const float* __restrict__ Wk,
    const float* __restrict__ Wv, const float* __restrict__ Wo,
    const float* __restrict__ W1,
    u16t* __restrict__ xb, u16t* __restrict__ WT, float* __restrict__ Beff)
{
    __shared__ float smf[1088];   // union: tile[32][33] (trans) | wm[2][256] (eff)
    int bidx = blockIdx.x;
    int t = threadIdx.x;
    if (bidx < 1024) {
        int idx = (bidx * 256 + t) * 4;
        float4 v = *(const float4*)(x + idx);
        u16t* o = xb + idx;
        o[0] = f2b(v.x); o[1] = f2b(v.y); o[2] = f2b(v.z); o[3] = f2b(v.w);
    } else if (bidx < 2048) {
        int t2 = bidx - 1024;
        int z = t2 >> 8, rem = t2 & 255;
        int n0 = (rem & 15) * 32, k0 = (rem >> 4) * 32;
        const float* W = z == 0 ? Wq : z == 1 ? Wk : z == 2 ? Wv : Wo;
        u16t* WTz = WT + (size_t)z * D_SZ * D_SZ;
        float (*tile)[33] = (float(*)[33])smf;
        int r = t >> 3, c4 = (t & 7) * 4;
        float4 v = *(const float4*)(W + (size_t)(k0 + r) * D_SZ + n0 + c4);
        tile[r][c4] = v.x; tile[r][c4 + 1] = v.y; tile[r][c4 + 2] = v.z; tile[r][c4 + 3] = v.w;
        __syncthreads();
        u16t o[4];
        o[0] = f2b(tile[c4][r]); o[1] = f2b(tile[c4 + 1][r]);
        o[2] = f2b(tile[c4 + 2][r]); o[3] = f2b(tile[c4 + 3][r]);
        *(ushort4*)(WTz + (size_t)(n0 + r) * D_SZ + k0 + c4) = *(ushort4*)o;
    } else {
        int k = bidx - 2048;   // 0..511
        float* wm0 = smf;
        float* wm1 = smf + 256;
        const float* wrq = Wq + (size_t)k * D_SZ;
        const float* wrk = Wk + (size_t)k * D_SZ;
        wm0[t & 255] = 0.5f * (wrq[t & 255] + wrq[(t & 255) + DH]);
        wm1[t & 255] = 0.5f * (wrk[t & 255] + wrk[(t & 255) + DH]);
        __syncthreads();
        int half = t >> 7, hcol = t & 127;
        const float* wm = half ? wm1 : wm0;
        const float* W1h = W1 + (half ? (size_t)DH * HH : 0);
        float s = 0.f;
        for (int d = 0; d < 256; ++d) s += wm[d] * W1h[(size_t)d * HH + hcol];
        Beff[(size_t)k * 256 + half * 128 + hcol] = s;
    }
}

// ---------------------------- 2-phase double-buffered GEMM mainloop (swizzled)
// C[BM=MF*64][BN=NF*16] per block (256 thr, 4 waves; wave w owns MF*16 rows).
// LDS physical slot p of row r holds logical 16B-slot p^(r&7): staged by
// swizzling the GLOBAL source column; frag reads use slot (kk*4+kg)^(r&7).
template<int MF, int NF>
static __device__ __forceinline__ void gemm_db(
    const u16t* __restrict__ A, int lda, const u16t* __restrict__ B, int ldb,
    int K, int tid, u16t* Als, u16t* Bls, f32x4 acc[MF][NF])
{
    const int w = tid >> 6, lane = tid & 63;
    const int lr = lane & 15, kg = lane >> 4;
    const int srow = lane >> 3;
    const int scol = ((lane & 7) ^ srow) * 8;   // swizzled global col (u16)
    const int ABUF = MF * 4096;   // u16 elems per A buffer
    const int BBUF = NF * 1024;   // u16 elems per B buffer
    auto stage = [&](int bb, int k0) {
#pragma unroll
        for (int q = 0; q < MF * 2; ++q) {
            int ci = w * (MF * 2) + q;
            gload16(A + (size_t)(ci * 8 + srow) * lda + k0 + scol,
                    Als + bb * ABUF + ci * 512);
        }
#pragma unroll
        for (int q = 0; q < NF / 2; ++q) {
            int cj = w * (NF / 2) + q;
            gload16(B + (size_t)(cj * 8 + srow) * ldb + k0 + scol,
                    Bls + bb * BBUF + cj * 512);
        }
    };
    stage(0, 0);
    __syncthreads();
    const int nt = K / 64;
    for (int t = 0; t < nt; ++t) {
        int cur = t & 1;
        if (t + 1 < nt) stage(cur ^ 1, (t + 1) * 64);
        const u16t* Ab = Als + cur * ABUF;
        const u16t* Bb = Bls + cur * BBUF;
#pragma unroll
        for (int kk = 0; kk < 2; ++kk) {
            bf16x8 af[MF], bfr[NF];
#pragma unroll
            for (int fi = 0; fi < MF; ++fi) {
                int r = w * (MF * 16) + fi * 16 + lr;
                af[fi] = *(const bf16x8*)(&Ab[r * 64 + (((kk * 4 + kg) ^ (r & 7)) << 3)]);
            }
#pragma unroll
            for (int fj = 0; fj < NF; ++fj) {
                int r = fj * 16 + lr;
                bfr[fj] = *(const bf16x8*)(&Bb[r * 64 + (((kk * 4 + kg) ^ (r & 7)) << 3)]);
            }
#pragma unroll
            for (int fi = 0; fi < MF; ++fi)
#pragma unroll
                for (int fj = 0; fj < NF; ++fj)
                    acc[fi][fj] = mfma16(af[fi], bfr[fj], acc[fi][fj]);
        }
        __syncthreads();
    }
}

// C-frag (fi,fj,rr): row = m0+w*MF*16+fi*16+kg*4+rr, col = n0+fj*16+lr  [m89]

// ------------------------------------------- K1: fused QKV GEMMs + mask-ac GEMM
// 1D grid, 640 blocks: [0,384) -> qkv (z = bid/128, MF=2); [384,640) -> ac.
__global__ __launch_bounds__(256) void k_qkvac(
    const u16t* __restrict__ xb, const u16t* __restrict__ WT,
    const float* __restrict__ x, const float* __restrict__ Beff,
    const float* __restrict__ b1,
    u16t* __restrict__ qb, u16t* __restrict__ kb, u16t* __restrict__ vT,
    float* __restrict__ a, float* __restrict__ cc)
{
    __shared__ __align__(16) char sm[49152];   // qkv: A 2x16KB + B 2x8KB = 48KB
    int bid = blockIdx.x;
    int t = threadIdx.x;
    if (bid < 384) {
        u16t* Als = (u16t*)sm;
        u16t* Bls = (u16t*)(sm + 32768);
        int z = bid / 128, rem = bid & 127;
        int m0 = (rem >> 3) * 128, n0 = (rem & 7) * 64;
        const u16t* A = xb + (size_t)m0 * D_SZ;
        const u16t* Bt = WT + (size_t)z * D_SZ * D_SZ + (size_t)n0 * D_SZ;
        f32x4 acc[2][4] = {};
        gemm_db<2, 4>(A, D_SZ, Bt, D_SZ, D_SZ, t, Als, Bls, acc);
        int w = t >> 6, lane = t & 63, lr = lane & 15, kg = lane >> 4;
        if (z < 2) {
            u16t (*vls)[68] = (u16t(*)[68])sm;
            float scale = z == 0 ? 0.0625f : 1.0f;
#pragma unroll
            for (int fi = 0; fi < 2; ++fi)
#pragma unroll
                for (int fj = 0; fj < 4; ++fj)
#pragma unroll
                    for (int rr = 0; rr < 4; ++rr)
                        vls[w * 32 + fi * 16 + kg * 4 + rr][fj * 16 + lr]
                            = f2b(acc[fi][fj][rr] * scale);
            __syncthreads();
            u16t* dst = z == 0 ? qb : kb;
            int c8 = (t & 7) * 8, r0 = t >> 3;
#pragma unroll
            for (int p = 0; p < 4; ++p) {
                int r = r0 + p * 32;
                *(uint4*)(dst + (size_t)(m0 + r) * D_SZ + n0 + c8) = *(const uint4*)(&vls[r][c8]);
            }
        } else {
            u16t (*vls)[136] = (u16t(*)[136])sm;   // 64*136*2 = 17408
#pragma unroll
            for (int fi = 0; fi < 2; ++fi)
#pragma unroll
                for (int fj = 0; fj < 4; ++fj)
#pragma unroll
                    for (int rr = 0; rr < 4; ++rr)
                        vls[fj * 16 + lr][w * 32 + fi * 16 + kg * 4 + rr] = f2b(acc[fi][fj][rr]);
            __syncthreads();
            int b = m0 >> 10, s0 = m0 & 1023;
            int cr = t >> 2, seg = t & 3;
            const u16t* srcp = &vls[cr][seg * 32];
            u16t* dstp = vT + (((size_t)(b * D_SZ + n0 + cr)) << 10) + s0 + seg * 32;
#pragma unroll
            for (int qq = 0; qq < 4; ++qq)
                *(uint4*)(dstp + qq * 8) = *(const uint4*)(srcp + qq * 8);
        }
    } else {
        // [a|c] = x @ Beff (f32), a gets +b1. 64 rows x 32 cols, 4x2/thread.
        float (*xs)[68] = (float(*)[68])sm;            // 64x68
        float (*bsT)[68] = (float(*)[68])(sm + 17408); // 32x68 [n][k]
        int t2 = bid - 384;
        int r0 = (t2 & 31) * 64, n0 = (t2 >> 5) * 32;
        int ti = t >> 4, tj = t & 15;
        float acc[4][2] = {};
        for (int k0 = 0; k0 < 512; k0 += 64) {
            if (k0) __syncthreads();
#pragma unroll
            for (int p = 0; p < 4; ++p) {
                int idx = t + p * 256;
                int r = idx >> 4, c4 = (idx & 15) * 4;
                *(float4*)&xs[r][c4] = *(const float4*)(x + (size_t)(r0 + r) * D_SZ + k0 + c4);
            }
#pragma unroll
            for (int p = 0; p < 2; ++p) {
                int idx = t + p * 256;
                int k = idx >> 3, n4 = (idx & 7) * 4;
                float4 v = *(const float4*)(Beff + (size_t)(k0 + k) * 256 + n0 + n4);
                bsT[n4][k] = v.x; bsT[n4 + 1][k] = v.y; bsT[n4 + 2][k] = v.z; bsT[n4 + 3][k] = v.w;
            }
            __syncthreads();
#pragma unroll
            for (int kk = 0; kk < 16; ++kk) {
                float4 xv[4], bv[2];
#pragma unroll
                for (int ri = 0; ri < 4; ++ri) xv[ri] = *(const float4*)&xs[ti + 16 * ri][kk * 4];
#pragma unroll
                for (int rj = 0; rj < 2; ++rj) bv[rj] = *(const float4*)&bsT[tj + 16 * rj][kk * 4];
#pragma unroll
                for (int ri = 0; ri < 4; ++ri)
#pragma unroll
                    for (int rj = 0; rj < 2; ++rj)
                        acc[ri][rj] += xv[ri].x * bv[rj].x + xv[ri].y * bv[rj].y
                                     + xv[ri].z * bv[rj].z + xv[ri].w * bv[rj].w;
            }
        }
        bool isA = n0 < 128;
#pragma unroll
        for (int rj = 0; rj < 2; ++rj) {
            int col = n0 + tj + 16 * rj;
            float badd = isA ? b1[col] : 0.f;
#pragma unroll
            for (int ri = 0; ri < 4; ++ri) {
                int row = r0 + ti + 16 * ri;
                if (isA) a[(size_t)row * HH + col] = acc[ri][rj] + badd;
                else     cc[(size_t)row * HH + (col - 128)] = acc[ri][rj];
            }
        }
    }
}

// -------------- K2: fused mask + both-head scores, PHASE-STAGGERED
// grid (16 jb, 16 mt, 2 b). Blocks with (jb^mt)&1 run GEMM->mask; others
// mask->GEMM (phases independent; both R12-identical internally).
__global__ __launch_bounds__(256) void k_scores(
    const u16t* __restrict__ qb, const u16t* __restrict__ kb,
    const float* __restrict__ a, const float* __restrict__ c,
    const float* __restrict__ W2, const float* __restrict__ b2,
    u16t* __restrict__ P, float* __restrict__ lpart)
{
    __shared__ __align__(16) char sm[55296];
    float (*at)[132] = (float(*)[132])sm;                       // 33792B
    float (*ct)[132] = (float(*)[132])(sm + 33792);             // 16896B (32 rows)
    unsigned char (*msk)[64] = (unsigned char(*)[64])(sm + 50688);  // 4096B
    float* w2s = (float*)(sm + 54784);                          // 512B
    int b = blockIdx.z, mt = blockIdx.y, jb = blockIdx.x;
    int m0 = mt * 64, j0 = jb * 64;
    int t = threadIdx.x;
    if (t < 128) w2s[t] = W2[t];
    float fb2 = b2[0];
    int ti = t >> 4, tj = t & 15;
    const int w = t >> 6, lane = t & 63, lr = lane & 15, kg = lane >> 4;
    const int srow = lane >> 3;
    const int scol = ((lane & 7) ^ srow) * 8;   // swizzled global col (u16)
    f32x4 acc0[4] = {}, acc1[4] = {};

    // ---- mask phase (R12-identical): at load + two jh-halves -> msk bits ----
    auto do_mask = [&]() {
#pragma unroll
        for (int p = 0; p < 8; ++p) {
            int idx = t + p * 256;
            int r = idx >> 5, c4 = (idx & 31) * 4;
            *(float4*)&at[r][c4] = *(const float4*)(a + ((size_t)(b * S_SZ + m0 + r)) * HH + c4);
        }
#pragma unroll
        for (int jh = 0; jh < 2; ++jh) {
            __syncthreads();   // jh=0: at/w2s visible; jh=1: prev ct readers done
#pragma unroll
            for (int p = 0; p < 4; ++p) {
                int idx = t + p * 256;
                int r = idx >> 5, c4 = (idx & 31) * 4;
                *(float4*)&ct[r][c4] =
                    *(const float4*)(c + ((size_t)(b * S_SZ + j0 + jh * 32 + r)) * HH + c4);
            }
            __syncthreads();
            float accm[4][2];
#pragma unroll
            for (int ri = 0; ri < 4; ++ri)
#pragma unroll
                for (int rj = 0; rj < 2; ++rj) accm[ri][rj] = fb2;
#pragma unroll 2
            for (int h4 = 0; h4 < 32; ++h4) {
                float4 wv = ((const float4*)w2s)[h4];
                float4 av[4], cv[2];
#pragma unroll
                for (int ri = 0; ri < 4; ++ri) av[ri] = *(const float4*)&at[ti + 16 * ri][h4 * 4];
#pragma unroll
                for (int rj = 0; rj < 2; ++rj) cv[rj] = *(const float4*)&ct[tj + 16 * rj][h4 * 4];
#pragma unroll
                for (int ri = 0; ri < 4; ++ri)
#pragma unroll
                    for (int rj = 0; rj < 2; ++rj) {
                        accm[ri][rj] += fmaxf(av[ri].x + cv[rj].x, 0.f) * wv.x;
                        accm[ri][rj] += fmaxf(av[ri].y + cv[rj].y, 0.f) * wv.y;
                        accm[ri][rj] += fmaxf(av[ri].z + cv[rj].z, 0.f) * wv.z;
                        accm[ri][rj] += fmaxf(av[ri].w + cv[rj].w, 0.f) * wv.w;
                    }
            }
#pragma unroll
            for (int ri = 0; ri < 4; ++ri)
#pragma unroll
                for (int rj = 0; rj < 2; ++rj)
                    msk[ti + 16 * ri][jh * 32 + tj + 16 * rj] = accm[ri][rj] > 0.f ? 1 : 0;
        }
    };

    // ---- GEMM phase (R12-identical): QK^T both heads, K=512 concat ----
    auto do_gemm = [&]() {
        __syncthreads();   // prior phase's LDS reads done; bufs overlay at/ct
        u16t* Als = (u16t*)sm;             // 2 x 8KB
        u16t* Bls = (u16t*)(sm + 16384);   // 2 x 8KB
        const u16t* A = qb + (size_t)(b * S_SZ + m0) * D_SZ;
        const u16t* B = kb + (size_t)(b * S_SZ + j0) * D_SZ;
        auto stage = [&](int bb, int k0) {
#pragma unroll
            for (int q = 0; q < 2; ++q) {
                int ci = w * 2 + q;
                gload16(A + (size_t)(ci * 8 + srow) * D_SZ + k0 + scol, Als + bb * 4096 + ci * 512);
                gload16(B + (size_t)(ci * 8 + srow) * D_SZ + k0 + scol, Bls + bb * 4096 + ci * 512);
            }
        };
        stage(0, 0);
        __syncthreads();
#pragma unroll
        for (int t8 = 0; t8 < 8; ++t8) {
            int cur = t8 & 1;
            if (t8 < 7) stage(cur ^ 1, (t8 + 1) * 64);
            const u16t* Ab = Als + cur * 4096;
            const u16t* Bb = Bls + cur * 4096;
#pragma unroll
            for (int kk = 0; kk < 2; ++kk) {
                int ra = w * 16 + lr;
                bf16x8 af = *(const bf16x8*)(&Ab[ra * 64 + (((kk * 4 + kg) ^ (ra & 7)) << 3)]);
                bf16x8 bfr[4];
#pragma unroll
                for (int fj = 0; fj < 4; ++fj) {
                    int rb = fj * 16 + lr;
                    bfr[fj] = *(const bf16x8*)(&Bb[rb * 64 + (((kk * 4 + kg) ^ (rb & 7)) << 3)]);
                }
                if (t8 < 4) {
#pragma unroll
                    for (int fj = 0; fj < 4; ++fj) acc0[fj] = mfma16(af, bfr[fj], acc0[fj]);
                } else {
#pragma unroll
                    for (int fj = 0; fj < 4; ++fj) acc1[fj] = mfma16(af, bfr[fj], acc1[fj]);
                }
            }
            __syncthreads();
        }
    };

    if ((jb ^ mt) & 1) { do_gemm(); do_mask(); }
    else               { do_mask(); do_gemm(); }
    __syncthreads();   // msk visible + all phase LDS traffic settled

    // ---- exp + mask + lpart + P store, per head (R12-identical) ----
    u16t (*vls)[68] = (u16t(*)[68])sm;   // 8704B, overlays GEMM bufs
#pragma unroll
    for (int h = 0; h < 2; ++h) {
#pragma unroll
        for (int rr = 0; rr < 4; ++rr) {
            int il = w * 16 + kg * 4 + rr;
            float rs = 0.f;
#pragma unroll
            for (int fj = 0; fj < 4; ++fj) {
                int jl = fj * 16 + lr;
                float s = h ? acc1[fj][rr] : acc0[fj][rr];
                float e = msk[il][jl] ? __expf(s) : 0.f;
                if (h) acc1[fj][rr] = e; else acc0[fj][rr] = e;
                rs += e;
            }
            rs += __shfl_xor(rs, 1); rs += __shfl_xor(rs, 2);
            rs += __shfl_xor(rs, 4); rs += __shfl_xor(rs, 8);
            if (lr == 0)
                lpart[((size_t)(jb * 4 + b * 2 + h) << 10) + m0 + il] = rs;
        }
#pragma unroll
        for (int fj = 0; fj < 4; ++fj)
#pragma unroll
            for (int rr = 0; rr < 4; ++rr)
                vls[w * 16 + kg * 4 + rr][fj * 16 + lr]
                    = f2b(h ? acc1[fj][rr] : acc0[fj][rr]);
        __syncthreads();
        int r = t >> 2, c16 = (t & 3) * 16;
        u16t* dstp = P + ((size_t)(b * 2 + h) << 20) + ((size_t)(m0 + r) << 10) + j0 + c16;
        *(uint4*)dstp = *(const uint4*)(&vls[r][c16]);
        *(uint4*)(dstp + 8) = *(const uint4*)(&vls[r][c16 + 8]);
        __syncthreads();
    }
}

// ----------------------------- K3: PV (+ diag(1/l) epilogue), BM=64
// grid (8,16,4): n0=x*32, m0=y*64.
__global__ __launch_bounds__(256) void k_pv(
    const u16t* __restrict__ P, const u16t* __restrict__ vT,
    const float* __restrict__ lpart, u16t* __restrict__ ao)
{
    __shared__ __align__(16) u16t sm[12288];   // A 2x8KB + B 2x4KB = 24KB
    __shared__ float invl[64];
    u16t* Als = sm;
    u16t* Bls = sm + 8192;
    int bh = blockIdx.z, b = bh >> 1, h = bh & 1;
    int m0 = blockIdx.y * 64, n0 = blockIdx.x * 32;
    int t = threadIdx.x;
    if (t < 64) {   // fixed-order row-sum over 16 j-block partials (deterministic)
        float l = 0.f;
        for (int jb = 0; jb < 16; ++jb)
            l += lpart[((size_t)(jb * 4 + bh) << 10) + m0 + t];
        invl[t] = l > 0.f ? 1.0f / l : 0.f;
    }
    const u16t* A = P + ((size_t)bh << 20) + (size_t)m0 * S_SZ;
    const u16t* Bt = vT + ((size_t)(b * D_SZ + h * DH + n0)) * S_SZ;
    f32x4 acc[1][2] = {};
    gemm_db<1, 2>(A, S_SZ, Bt, S_SZ, S_SZ, t, Als, Bls, acc);
    int w = t >> 6, lane = t & 63, lr = lane & 15, kg = lane >> 4;
    u16t (*ols)[40] = (u16t(*)[40])sm;   // 64x40 u16 = 5120B
#pragma unroll
    for (int fj = 0; fj < 2; ++fj)
#pragma unroll
        for (int rr = 0; rr < 4; ++rr) {
            int rl = w * 16 + kg * 4 + rr;
            ols[rl][fj * 16 + lr] = f2b(acc[0][fj][rr] * invl[rl]);
        }
    __syncthreads();
    int r = t >> 2, c8 = (t & 3) * 8;
    *(uint4*)(ao + ((size_t)(b * S_SZ + m0 + r)) * D_SZ + h * DH + n0 + c8)
        = *(const uint4*)(&ols[r][c8]);
}

// ------------------------------------------ K4: out = ao@Wo+bo, BM=64
// grid (16,32): n0=x*32, m0=y*64.
__global__ __launch_bounds__(256) void k_out(
    const u16t* __restrict__ ao, const u16t* __restrict__ WoT,
    const float* __restrict__ bo, float* __restrict__ out)
{
    __shared__ __align__(16) u16t sm[12288];   // A 2x8KB + B 2x4KB = 24KB
    u16t* Als = sm;
    u16t* Bls = sm + 8192;
    int m0 = blockIdx.y * 64, n0 = blockIdx.x * 32;
    const u16t* A = ao + (size_t)m0 * D_SZ;
    const u16t* Bt = WoT + (size_t)n0 * D_SZ;
    f32x4 acc[1][2] = {};
    gemm_db<1, 2>(A, D_SZ, Bt, D_SZ, D_SZ, threadIdx.x, Als, Bls, acc);
    int w = threadIdx.x >> 6, lane = threadIdx.x & 63, lr = lane & 15, kg = lane >> 4;
    float (*ols)[36] = (float(*)[36])sm;   // 64x36 f32 = 9216B
#pragma unroll
    for (int fj = 0; fj < 2; ++fj)
#pragma unroll
        for (int rr = 0; rr < 4; ++rr) {
            int rl = w * 16 + kg * 4 + rr;
            ols[rl][fj * 16 + lr] = acc[0][fj][rr] + bo[n0 + fj * 16 + lr];
        }
    __syncthreads();
    int r0 = threadIdx.x >> 3, c4 = (threadIdx.x & 7) * 4;
#pragma unroll
    for (int p = 0; p < 2; ++p) {
        int r = r0 + p * 32;
        *(float4*)(out + (size_t)(m0 + r) * D_SZ + n0 + c4) = *(const float4*)(&ols[r][c4]);
    }
}

// ---------------------------------------------------------------------- host
extern "C" void kernel_launch(void* const* d_in, const int* in_sizes, int n_in,
                              void* d_out, int out_size, void* d_ws, size_t ws_size,
                              hipStream_t stream)
{
    const float* x  = (const float*)d_in[0];
    const float* Wq = (const float*)d_in[1];
    const float* Wk = (const float*)d_in[2];
    const float* Wv = (const float*)d_in[3];
    const float* Wo = (const float*)d_in[4];
    const float* bo = (const float*)d_in[5];
    const float* W1 = (const float*)d_in[6];
    const float* b1 = (const float*)d_in[7];
    const float* W2 = (const float*)d_in[8];
    const float* b2 = (const float*)d_in[9];
    float* out = (float*)d_out;

    // workspace carve (all 256B-aligned)
    char* ws = (char*)d_ws;
    size_t off = 0;
    auto carve = [&](size_t bytes) { void* p = ws + off; off += (bytes + 255) & ~(size_t)255; return p; };
    u16t* xb   = (u16t*)carve((size_t)2048 * 512 * 2);
    u16t* WT   = (u16t*)carve((size_t)4 * 512 * 512 * 2);
    u16t* qb   = (u16t*)carve((size_t)2048 * 512 * 2);
    u16t* kb   = (u16t*)carve((size_t)2048 * 512 * 2);
    u16t* vT   = (u16t*)carve((size_t)2 * 512 * 1024 * 2);
    float* Beff = (float*)carve((size_t)512 * 256 * 4);
    float* a   = (float*)carve((size_t)2048 * 128 * 4);
    float* c   = (float*)carve((size_t)2048 * 128 * 4);
    u16t* P    = (u16t*)carve((size_t)4 * 1024 * 1024 * 2);
    float* lpart = (float*)carve((size_t)16 * 4 * 1024 * 4);
    u16t* ao   = (u16t*)carve((size_t)2048 * 512 * 2);
    (void)ws_size;

    k_prep<<<dim3(2560), dim3(256), 0, stream>>>(x, Wq, Wk, Wv, Wo, W1, xb, WT, Beff);
    k_qkvac<<<dim3(640), dim3(256), 0, stream>>>(xb, WT, x, Beff, b1, qb, kb, vT, a, c);
    k_scores<<<dim3(16, 16, 2), dim3(256), 0, stream>>>(qb, kb, a, c, W2, b2, P, lpart);
    k_pv<<<dim3(8, 16, 4), dim3(256), 0, stream>>>(P, vT, lpart, ao);
    k_out<<<dim3(16, 32), dim3(256), 0, stream>>>(ao, WT + (size_t)3 * 512 * 512, bo, out);
}

// Round 16
// 99.892 us; speedup vs baseline: 1.4307x; 1.0090x over previous
//
#include <hip/hip_runtime.h>

// AdaptiveSparsityAttention on MI355X (gfx950).
// f32 in/out, internal bf16 MFMA; mask logits in pure f32 via algebraic
// fusion:  a = x @ (0.5*(Wq[:,:256]+Wq[:,256:]) @ W1[:256]) + b1.
//
// R16 (base = R12 @100.3us): k_scores BM 64 -> 32, grid 512 -> 1024.
//   R13/R15 profiles: k_scores is latency-bound with OccupancyPercent ~18%
//   — GRID-capped at 2 blocks/CU, not LDS-capped. BM=32 doubles real
//   concurrency (4 blk/CU), halves per-thread live state (VGPR ~60),
//   LDS 36KB. Waves partition j; cross-wave row-sum via lsum[4][32] LDS
//   (fixed order, deterministic). Mask/QK^T per-pair arithmetic identical.
// 5 launches: prep, qkvac, scores, pv, out.

typedef unsigned short u16t;
typedef __bf16 bf16x8 __attribute__((ext_vector_type(8)));
typedef float f32x4 __attribute__((ext_vector_type(4)));

#define B_SZ 2
#define S_SZ 1024
#define D_SZ 512
#define DH 256
#define HH 128   // hidden dim of sparsity predictor

static __device__ __forceinline__ u16t f2b(float f) {
    unsigned int u = __builtin_bit_cast(unsigned int, f);
    u += 0x7FFFu + ((u >> 16) & 1u);
    return (u16t)(u >> 16);
}

static __device__ __forceinline__ f32x4 mfma16(bf16x8 a, bf16x8 b, f32x4 c) {
    return __builtin_amdgcn_mfma_f32_16x16x32_bf16(a, b, c, 0, 0, 0);
}

static __device__ __forceinline__ void gload16(const void* g, void* l) {
    __builtin_amdgcn_global_load_lds(
        (const __attribute__((address_space(1))) void*)g,
        (__attribute__((address_space(3))) void*)l, 16, 0, 0);
}

// ---------------------------------------------------------- K0: fused prep
// blocks [0,1024): x->bf16 | [1024,2048): W transposes | [2048,2560): Beff
__global__ __launch_bounds__(256) void k_prep(
    const float* __restrict__ x,
    const float* __restrict__ Wq, const float* __restrict__ Wk,
    const float* __restrict__ Wv, const float* __restrict__ Wo,
    const float* __restrict__ W1,
    u16t* __restrict__ xb, u16t* __restrict__ WT, float* __restrict__ Beff)
{
    __shared__ float smf[1088];   // union: tile[32][33] (trans) | wm[2][256] (eff)
    int bidx = blockIdx.x;
    int t = threadIdx.x;
    if (bidx < 1024) {
        int idx = (bidx * 256 + t) * 4;
        float4 v = *(const float4*)(x + idx);
        u16t* o = xb + idx;
        o[0] = f2b(v.x); o[1] = f2b(v.y); o[2] = f2b(v.z); o[3] = f2b(v.w);
    } else if (bidx < 2048) {
        int t2 = bidx - 1024;
        int z = t2 >> 8, rem = t2 & 255;
        int n0 = (rem & 15) * 32, k0 = (rem >> 4) * 32;
        const float* W = z == 0 ? Wq : z == 1 ? Wk : z == 2 ? Wv : Wo;
        u16t* WTz = WT + (size_t)z * D_SZ * D_SZ;
        float (*tile)[33] = (float(*)[33])smf;
        int r = t >> 3, c4 = (t & 7) * 4;
        float4 v = *(const float4*)(W + (size_t)(k0 + r) * D_SZ + n0 + c4);
        tile[r][c4] = v.x; tile[r][c4 + 1] = v.y; tile[r][c4 + 2] = v.z; tile[r][c4 + 3] = v.w;
        __syncthreads();
        u16t o[4];
        o[0] = f2b(tile[c4][r]); o[1] = f2b(tile[c4 + 1][r]);
        o[2] = f2b(tile[c4 + 2][r]); o[3] = f2b(tile[c4 + 3][r]);
        *(ushort4*)(WTz + (size_t)(n0 + r) * D_SZ + k0 + c4) = *(ushort4*)o;
    } else {
        int k = bidx - 2048;   // 0..511
        float* wm0 = smf;
        float* wm1 = smf + 256;
        const float* wrq = Wq + (size_t)k * D_SZ;
        const float* wrk = Wk + (size_t)k * D_SZ;
        wm0[t & 255] = 0.5f * (wrq[t & 255] + wrq[(t & 255) + DH]);
        wm1[t & 255] = 0.5f * (wrk[t & 255] + wrk[(t & 255) + DH]);
        __syncthreads();
        int half = t >> 7, hcol = t & 127;
        const float* wm = half ? wm1 : wm0;
        const float* W1h = W1 + (half ? (size_t)DH * HH : 0);
        float s = 0.f;
        for (int d = 0; d < 256; ++d) s += wm[d] * W1h[(size_t)d * HH + hcol];
        Beff[(size_t)k * 256 + half * 128 + hcol] = s;
    }
}

// ---------------------------- 2-phase double-buffered GEMM mainloop (swizzled)
// C[BM=MF*64][BN=NF*16] per block (256 thr, 4 waves; wave w owns MF*16 rows).
// LDS physical slot p of row r holds logical 16B-slot p^(r&7): staged by
// swizzling the GLOBAL source column; frag reads use slot (kk*4+kg)^(r&7).
template<int MF, int NF>
static __device__ __forceinline__ void gemm_db(
    const u16t* __restrict__ A, int lda, const u16t* __restrict__ B, int ldb,
    int K, int tid, u16t* Als, u16t* Bls, f32x4 acc[MF][NF])
{
    const int w = tid >> 6, lane = tid & 63;
    const int lr = lane & 15, kg = lane >> 4;
    const int srow = lane >> 3;
    const int scol = ((lane & 7) ^ srow) * 8;   // swizzled global col (u16)
    const int ABUF = MF * 4096;   // u16 elems per A buffer
    const int BBUF = NF * 1024;   // u16 elems per B buffer
    auto stage = [&](int bb, int k0) {
#pragma unroll
        for (int q = 0; q < MF * 2; ++q) {
            int ci = w * (MF * 2) + q;
            gload16(A + (size_t)(ci * 8 + srow) * lda + k0 + scol,
                    Als + bb * ABUF + ci * 512);
        }
#pragma unroll
        for (int q = 0; q < NF / 2; ++q) {
            int cj = w * (NF / 2) + q;
            gload16(B + (size_t)(cj * 8 + srow) * ldb + k0 + scol,
                    Bls + bb * BBUF + cj * 512);
        }
    };
    stage(0, 0);
    __syncthreads();
    const int nt = K / 64;
    for (int t = 0; t < nt; ++t) {
        int cur = t & 1;
        if (t + 1 < nt) stage(cur ^ 1, (t + 1) * 64);
        const u16t* Ab = Als + cur * ABUF;
        const u16t* Bb = Bls + cur * BBUF;
#pragma unroll
        for (int kk = 0; kk < 2; ++kk) {
            bf16x8 af[MF], bfr[NF];
#pragma unroll
            for (int fi = 0; fi < MF; ++fi) {
                int r = w * (MF * 16) + fi * 16 + lr;
                af[fi] = *(const bf16x8*)(&Ab[r * 64 + (((kk * 4 + kg) ^ (r & 7)) << 3)]);
            }
#pragma unroll
            for (int fj = 0; fj < NF; ++fj) {
                int r = fj * 16 + lr;
                bfr[fj] = *(const bf16x8*)(&Bb[r * 64 + (((kk * 4 + kg) ^ (r & 7)) << 3)]);
            }
#pragma unroll
            for (int fi = 0; fi < MF; ++fi)
#pragma unroll
                for (int fj = 0; fj < NF; ++fj)
                    acc[fi][fj] = mfma16(af[fi], bfr[fj], acc[fi][fj]);
        }
        __syncthreads();
    }
}

// C-frag (fi,fj,rr): row = m0+w*MF*16+fi*16+kg*4+rr, col = n0+fj*16+lr  [m89]

// ------------------------------------------- K1: fused QKV GEMMs + mask-ac GEMM
// 1D grid, 640 blocks: [0,384) -> qkv (z = bid/128, MF=2); [384,640) -> ac.
__global__ __launch_bounds__(256) void k_qkvac(
    const u16t* __restrict__ xb, const u16t* __restrict__ WT,
    const float* __restrict__ x, const float* __restrict__ Beff,
    const float* __restrict__ b1,
    u16t* __restrict__ qb, u16t* __restrict__ kb, u16t* __restrict__ vT,
    float* __restrict__ a, float* __restrict__ cc)
{
    __shared__ __align__(16) char sm[49152];   // qkv: A 2x16KB + B 2x8KB = 48KB
    int bid = blockIdx.x;
    int t = threadIdx.x;
    if (bid < 384) {
        u16t* Als = (u16t*)sm;
        u16t* Bls = (u16t*)(sm + 32768);
        int z = bid / 128, rem = bid & 127;
        int m0 = (rem >> 3) * 128, n0 = (rem & 7) * 64;
        const u16t* A = xb + (size_t)m0 * D_SZ;
        const u16t* Bt = WT + (size_t)z * D_SZ * D_SZ + (size_t)n0 * D_SZ;
        f32x4 acc[2][4] = {};
        gemm_db<2, 4>(A, D_SZ, Bt, D_SZ, D_SZ, t, Als, Bls, acc);
        int w = t >> 6, lane = t & 63, lr = lane & 15, kg = lane >> 4;
        if (z < 2) {
            u16t (*vls)[68] = (u16t(*)[68])sm;
            float scale = z == 0 ? 0.0625f : 1.0f;
#pragma unroll
            for (int fi = 0; fi < 2; ++fi)
#pragma unroll
                for (int fj = 0; fj < 4; ++fj)
#pragma unroll
                    for (int rr = 0; rr < 4; ++rr)
                        vls[w * 32 + fi * 16 + kg * 4 + rr][fj * 16 + lr]
                            = f2b(acc[fi][fj][rr] * scale);
            __syncthreads();
            u16t* dst = z == 0 ? qb : kb;
            int c8 = (t & 7) * 8, r0 = t >> 3;
#pragma unroll
            for (int p = 0; p < 4; ++p) {
                int r = r0 + p * 32;
                *(uint4*)(dst + (size_t)(m0 + r) * D_SZ + n0 + c8) = *(const uint4*)(&vls[r][c8]);
            }
        } else {
            u16t (*vls)[136] = (u16t(*)[136])sm;   // 64*136*2 = 17408
#pragma unroll
            for (int fi = 0; fi < 2; ++fi)
#pragma unroll
                for (int fj = 0; fj < 4; ++fj)
#pragma unroll
                    for (int rr = 0; rr < 4; ++rr)
                        vls[fj * 16 + lr][w * 32 + fi * 16 + kg * 4 + rr] = f2b(acc[fi][fj][rr]);
            __syncthreads();
            int b = m0 >> 10, s0 = m0 & 1023;
            int cr = t >> 2, seg = t & 3;
            const u16t* srcp = &vls[cr][seg * 32];
            u16t* dstp = vT + (((size_t)(b * D_SZ + n0 + cr)) << 10) + s0 + seg * 32;
#pragma unroll
            for (int qq = 0; qq < 4; ++qq)
                *(uint4*)(dstp + qq * 8) = *(const uint4*)(srcp + qq * 8);
        }
    } else {
        // [a|c] = x @ Beff (f32), a gets +b1. 64 rows x 32 cols, 4x2/thread.
        float (*xs)[68] = (float(*)[68])sm;            // 64x68
        float (*bsT)[68] = (float(*)[68])(sm + 17408); // 32x68 [n][k]
        int t2 = bid - 384;
        int r0 = (t2 & 31) * 64, n0 = (t2 >> 5) * 32;
        int ti = t >> 4, tj = t & 15;
        float acc[4][2] = {};
        for (int k0 = 0; k0 < 512; k0 += 64) {
            if (k0) __syncthreads();
#pragma unroll
            for (int p = 0; p < 4; ++p) {
                int idx = t + p * 256;
                int r = idx >> 4, c4 = (idx & 15) * 4;
                *(float4*)&xs[r][c4] = *(const float4*)(x + (size_t)(r0 + r) * D_SZ + k0 + c4);
            }
#pragma unroll
            for (int p = 0; p < 2; ++p) {
                int idx = t + p * 256;
                int k = idx >> 3, n4 = (idx & 7) * 4;
                float4 v = *(const float4*)(Beff + (size_t)(k0 + k) * 256 + n0 + n4);
                bsT[n4][k] = v.x; bsT[n4 + 1][k] = v.y; bsT[n4 + 2][k] = v.z; bsT[n4 + 3][k] = v.w;
            }
            __syncthreads();
#pragma unroll
            for (int kk = 0; kk < 16; ++kk) {
                float4 xv[4], bv[2];
#pragma unroll
                for (int ri = 0; ri < 4; ++ri) xv[ri] = *(const float4*)&xs[ti + 16 * ri][kk * 4];
#pragma unroll
                for (int rj = 0; rj < 2; ++rj) bv[rj] = *(const float4*)&bsT[tj + 16 * rj][kk * 4];
#pragma unroll
                for (int ri = 0; ri < 4; ++ri)
#pragma unroll
                    for (int rj = 0; rj < 2; ++rj)
                        acc[ri][rj] += xv[ri].x * bv[rj].x + xv[ri].y * bv[rj].y
                                     + xv[ri].z * bv[rj].z + xv[ri].w * bv[rj].w;
            }
        }
        bool isA = n0 < 128;
#pragma unroll
        for (int rj = 0; rj < 2; ++rj) {
            int col = n0 + tj + 16 * rj;
            float badd = isA ? b1[col] : 0.f;
#pragma unroll
            for (int ri = 0; ri < 4; ++ri) {
                int row = r0 + ti + 16 * ri;
                if (isA) a[(size_t)row * HH + col] = acc[ri][rj] + badd;
                else     cc[(size_t)row * HH + (col - 128)] = acc[ri][rj];
            }
        }
    }
}

// -------------- K2: fused mask + both-head scores, BM=32
// grid (16 jb, 32 mt, 2 b) = 1024 blocks. Phase 1: 32x64 mask tile (two
// jh-halves, at/ct[32][132] in LDS). Phase 2: QK^T h0+h1 (K=512 concat,
// swizzled db LDS; waves partition j). Phase 3: exp+mask -> P + lpart
// (cross-wave lsum reduce, fixed order). LDS 36KB.
__global__ __launch_bounds__(256) void k_scores(
    const u16t* __restrict__ qb, const u16t* __restrict__ kb,
    const float* __restrict__ a, const float* __restrict__ c,
    const float* __restrict__ W2, const float* __restrict__ b2,
    u16t* __restrict__ P, float* __restrict__ lpart)
{
    __shared__ __align__(16) char sm[36864];
    float (*at)[132] = (float(*)[132])sm;                       // 16896B
    float (*ct)[132] = (float(*)[132])(sm + 16896);             // 16896B
    unsigned char (*msk)[64] = (unsigned char(*)[64])(sm + 33792);  // 2048B persists
    float* w2s  = (float*)(sm + 35840);                         // 512B persists
    float* lsum = (float*)(sm + 36352);                         // 4x32 f32 = 512B
    int b = blockIdx.z, mt = blockIdx.y, jb = blockIdx.x;
    int m0 = mt * 32, j0 = jb * 64;
    int t = threadIdx.x;
    if (t < 128) w2s[t] = W2[t];
    float fb2 = b2[0];
    int ti = t >> 4, tj = t & 15;
    // load a-tile (32 rows)
#pragma unroll
    for (int p = 0; p < 4; ++p) {
        int idx = t + p * 256;
        int r = idx >> 5, c4 = (idx & 31) * 4;
        *(float4*)&at[r][c4] = *(const float4*)(a + ((size_t)(b * S_SZ + m0 + r)) * HH + c4);
    }
    // ---- phase 1: mask tile (two j-halves of 32) ----
#pragma unroll
    for (int jh = 0; jh < 2; ++jh) {
        __syncthreads();   // jh=0: at/w2s visible; jh=1: prev ct readers done
#pragma unroll
        for (int p = 0; p < 4; ++p) {
            int idx = t + p * 256;
            int r = idx >> 5, c4 = (idx & 31) * 4;
            *(float4*)&ct[r][c4] =
                *(const float4*)(c + ((size_t)(b * S_SZ + j0 + jh * 32 + r)) * HH + c4);
        }
        __syncthreads();
        float accm[2][2];
#pragma unroll
        for (int ri = 0; ri < 2; ++ri)
#pragma unroll
            for (int rj = 0; rj < 2; ++rj) accm[ri][rj] = fb2;
#pragma unroll 2
        for (int h4 = 0; h4 < 32; ++h4) {
            float4 wv = ((const float4*)w2s)[h4];
            float4 av[2], cv[2];
#pragma unroll
            for (int ri = 0; ri < 2; ++ri) av[ri] = *(const float4*)&at[ti + 16 * ri][h4 * 4];
#pragma unroll
            for (int rj = 0; rj < 2; ++rj) cv[rj] = *(const float4*)&ct[tj + 16 * rj][h4 * 4];
#pragma unroll
            for (int ri = 0; ri < 2; ++ri)
#pragma unroll
                for (int rj = 0; rj < 2; ++rj) {
                    accm[ri][rj] += fmaxf(av[ri].x + cv[rj].x, 0.f) * wv.x;
                    accm[ri][rj] += fmaxf(av[ri].y + cv[rj].y, 0.f) * wv.y;
                    accm[ri][rj] += fmaxf(av[ri].z + cv[rj].z, 0.f) * wv.z;
                    accm[ri][rj] += fmaxf(av[ri].w + cv[rj].w, 0.f) * wv.w;
                }
        }
#pragma unroll
        for (int ri = 0; ri < 2; ++ri)
#pragma unroll
            for (int rj = 0; rj < 2; ++rj)
                msk[ti + 16 * ri][jh * 32 + tj + 16 * rj] = accm[ri][rj] > 0.f ? 1 : 0;
    }
    __syncthreads();   // at/ct readers done; GEMM bufs overlay at/ct space
    // ---- phase 2: QK^T both heads (K=512 concat; qb pre-scaled by 1/16) ----
    // Waves partition j: wave w owns j-frag w (cols w*16..+16), all of M=32.
    u16t* Als = (u16t*)sm;             // 2 x 4KB
    u16t* Bls = (u16t*)(sm + 8192);    // 2 x 8KB
    const u16t* A = qb + (size_t)(b * S_SZ + m0) * D_SZ;
    const u16t* B = kb + (size_t)(b * S_SZ + j0) * D_SZ;
    const int w = t >> 6, lane = t & 63, lr = lane & 15, kg = lane >> 4;
    const int srow = lane >> 3;
    const int scol = ((lane & 7) ^ srow) * 8;   // swizzled global col (u16)
    auto stage = [&](int bb, int k0) {
        gload16(A + (size_t)(w * 8 + srow) * D_SZ + k0 + scol, Als + bb * 2048 + w * 512);
#pragma unroll
        for (int q = 0; q < 2; ++q) {
            int cj = w * 2 + q;
            gload16(B + (size_t)(cj * 8 + srow) * D_SZ + k0 + scol, Bls + bb * 4096 + cj * 512);
        }
    };
    f32x4 acc0[2] = {}, acc1[2] = {};
    stage(0, 0);
    __syncthreads();
#pragma unroll
    for (int t8 = 0; t8 < 8; ++t8) {
        int cur = t8 & 1;
        if (t8 < 7) stage(cur ^ 1, (t8 + 1) * 64);
        const u16t* Ab = Als + cur * 2048;
        const u16t* Bb = Bls + cur * 4096;
#pragma unroll
        for (int kk = 0; kk < 2; ++kk) {
            int rb = w * 16 + lr;
            bf16x8 bfr = *(const bf16x8*)(&Bb[rb * 64 + (((kk * 4 + kg) ^ (rb & 7)) << 3)]);
            bf16x8 af[2];
#pragma unroll
            for (int fi = 0; fi < 2; ++fi) {
                int ra = fi * 16 + lr;
                af[fi] = *(const bf16x8*)(&Ab[ra * 64 + (((kk * 4 + kg) ^ (ra & 7)) << 3)]);
            }
            if (t8 < 4) {
#pragma unroll
                for (int fi = 0; fi < 2; ++fi) acc0[fi] = mfma16(af[fi], bfr, acc0[fi]);
            } else {
#pragma unroll
                for (int fi = 0; fi < 2; ++fi) acc1[fi] = mfma16(af[fi], bfr, acc1[fi]);
            }
        }
        __syncthreads();
    }
    // ---- phase 3: exp + mask + lpart + P store, per head ----
    // thread value (h, fi, rr): i_local = fi*16+kg*4+rr, j_local = w*16+lr
    u16t (*vls)[68] = (u16t(*)[68])sm;   // 32x68 u16 = 4352B, overlays GEMM bufs
#pragma unroll
    for (int h = 0; h < 2; ++h) {
#pragma unroll
        for (int fi = 0; fi < 2; ++fi)
#pragma unroll
            for (int rr = 0; rr < 4; ++rr) {
                int il = fi * 16 + kg * 4 + rr;
                int jl = w * 16 + lr;
                float s = h ? acc1[fi][rr] : acc0[fi][rr];
                float e = msk[il][jl] ? __expf(s) : 0.f;
                if (h) acc1[fi][rr] = e; else acc0[fi][rr] = e;
            }
        // per-wave partial row sums -> lsum[w][il]
#pragma unroll
        for (int fi = 0; fi < 2; ++fi)
#pragma unroll
            for (int rr = 0; rr < 4; ++rr) {
                float rs = h ? acc1[fi][rr] : acc0[fi][rr];
                rs += __shfl_xor(rs, 1); rs += __shfl_xor(rs, 2);
                rs += __shfl_xor(rs, 4); rs += __shfl_xor(rs, 8);
                if (lr == 0) lsum[w * 32 + fi * 16 + kg * 4 + rr] = rs;
            }
        __syncthreads();
        if (t < 32) {   // fixed-order cross-wave sum (deterministic)
            float l = lsum[t] + lsum[32 + t] + lsum[64 + t] + lsum[96 + t];
            lpart[((size_t)(jb * 4 + b * 2 + h) << 10) + m0 + t] = l;
        }
        // stage P tile + coalesced store
#pragma unroll
        for (int fi = 0; fi < 2; ++fi)
#pragma unroll
            for (int rr = 0; rr < 4; ++rr)
                vls[fi * 16 + kg * 4 + rr][w * 16 + lr]
                    = f2b(h ? acc1[fi][rr] : acc0[fi][rr]);
        __syncthreads();
        int r = t >> 3, c8 = (t & 7) * 8;
        *(uint4*)(P + ((size_t)(b * 2 + h) << 20) + ((size_t)(m0 + r) << 10) + j0 + c8)
            = *(const uint4*)(&vls[r][c8]);
        __syncthreads();
    }
}

// ----------------------------- K3: PV (+ diag(1/l) epilogue), BM=64
// grid (8,16,4): n0=x*32, m0=y*64.
__global__ __launch_bounds__(256) void k_pv(
    const u16t* __restrict__ P, const u16t* __restrict__ vT,
    const float* __restrict__ lpart, u16t* __restrict__ ao)
{
    __shared__ __align__(16) u16t sm[12288];   // A 2x8KB + B 2x4KB = 24KB
    __shared__ float invl[64];
    u16t* Als = sm;
    u16t* Bls = sm + 8192;
    int bh = blockIdx.z, b = bh >> 1, h = bh & 1;
    int m0 = blockIdx.y * 64, n0 = blockIdx.x * 32;
    int t = threadIdx.x;
    if (t < 64) {   // fixed-order row-sum over 16 j-block partials (deterministic)
        float l = 0.f;
        for (int jb = 0; jb < 16; ++jb)
            l += lpart[((size_t)(jb * 4 + bh) << 10) + m0 + t];
        invl[t] = l > 0.f ? 1.0f / l : 0.f;
    }
    const u16t* A = P + ((size_t)bh << 20) + (size_t)m0 * S_SZ;
    const u16t* Bt = vT + ((size_t)(b * D_SZ + h * DH + n0)) * S_SZ;
    f32x4 acc[1][2] = {};
    gemm_db<1, 2>(A, S_SZ, Bt, S_SZ, S_SZ, t, Als, Bls, acc);
    int w = t >> 6, lane = t & 63, lr = lane & 15, kg = lane >> 4;
    u16t (*ols)[40] = (u16t(*)[40])sm;   // 64x40 u16 = 5120B
#pragma unroll
    for (int fj = 0; fj < 2; ++fj)
#pragma unroll
        for (int rr = 0; rr < 4; ++rr) {
            int rl = w * 16 + kg * 4 + rr;
            ols[rl][fj * 16 + lr] = f2b(acc[0][fj][rr] * invl[rl]);
        }
    __syncthreads();
    int r = t >> 2, c8 = (t & 3) * 8;
    *(uint4*)(ao + ((size_t)(b * S_SZ + m0 + r)) * D_SZ + h * DH + n0 + c8)
        = *(const uint4*)(&ols[r][c8]);
}

// ------------------------------------------ K4: out = ao@Wo+bo, BM=64
// grid (16,32): n0=x*32, m0=y*64.
__global__ __launch_bounds__(256) void k_out(
    const u16t* __restrict__ ao, const u16t* __restrict__ WoT,
    const float* __restrict__ bo, float* __restrict__ out)
{
    __shared__ __align__(16) u16t sm[12288];   // A 2x8KB + B 2x4KB = 24KB
    u16t* Als = sm;
    u16t* Bls = sm + 8192;
    int m0 = blockIdx.y * 64, n0 = blockIdx.x * 32;
    const u16t* A = ao + (size_t)m0 * D_SZ;
    const u16t* Bt = WoT + (size_t)n0 * D_SZ;
    f32x4 acc[1][2] = {};
    gemm_db<1, 2>(A, D_SZ, Bt, D_SZ, D_SZ, threadIdx.x, Als, Bls, acc);
    int w = threadIdx.x >> 6, lane = threadIdx.x & 63, lr = lane & 15, kg = lane >> 4;
    float (*ols)[36] = (float(*)[36])sm;   // 64x36 f32 = 9216B
#pragma unroll
    for (int fj = 0; fj < 2; ++fj)
#pragma unroll
        for (int rr = 0; rr < 4; ++rr) {
            int rl = w * 16 + kg * 4 + rr;
            ols[rl][fj * 16 + lr] = acc[0][fj][rr] + bo[n0 + fj * 16 + lr];
        }
    __syncthreads();
    int r0 = threadIdx.x >> 3, c4 = (threadIdx.x & 7) * 4;
#pragma unroll
    for (int p = 0; p < 2; ++p) {
        int r = r0 + p * 32;
        *(float4*)(out + (size_t)(m0 + r) * D_SZ + n0 + c4) = *(const float4*)(&ols[r][c4]);
    }
}

// ---------------------------------------------------------------------- host
extern "C" void kernel_launch(void* const* d_in, const int* in_sizes, int n_in,
                              void* d_out, int out_size, void* d_ws, size_t ws_size,
                              hipStream_t stream)
{
    const float* x  = (const float*)d_in[0];
    const float* Wq = (const float*)d_in[1];
    const float* Wk = (const float*)d_in[2];
    const float* Wv = (const float*)d_in[3];
    const float* Wo = (const float*)d_in[4];
    const float* bo = (const float*)d_in[5];
    const float* W1 = (const float*)d_in[6];
    const float* b1 = (const float*)d_in[7];
    const float* W2 = (const float*)d_in[8];
    const float* b2 = (const float*)d_in[9];
    float* out = (float*)d_out;

    // workspace carve (all 256B-aligned)
    char* ws = (char*)d_ws;
    size_t off = 0;
    auto carve = [&](size_t bytes) { void* p = ws + off; off += (bytes + 255) & ~(size_t)255; return p; };
    u16t* xb   = (u16t*)carve((size_t)2048 * 512 * 2);
    u16t* WT   = (u16t*)carve((size_t)4 * 512 * 512 * 2);
    u16t* qb   = (u16t*)carve((size_t)2048 * 512 * 2);
    u16t* kb   = (u16t*)carve((size_t)2048 * 512 * 2);
    u16t* vT   = (u16t*)carve((size_t)2 * 512 * 1024 * 2);
    float* Beff = (float*)carve((size_t)512 * 256 * 4);
    float* a   = (float*)carve((size_t)2048 * 128 * 4);
    float* c   = (float*)carve((size_t)2048 * 128 * 4);
    u16t* P    = (u16t*)carve((size_t)4 * 1024 * 1024 * 2);
    float* lpart = (float*)carve((size_t)16 * 4 * 1024 * 4);
    u16t* ao   = (u16t*)carve((size_t)2048 * 512 * 2);
    (void)ws_size;

    k_prep<<<dim3(2560), dim3(256), 0, stream>>>(x, Wq, Wk, Wv, Wo, W1, xb, WT, Beff);
    k_qkvac<<<dim3(640), dim3(256), 0, stream>>>(xb, WT, x, Beff, b1, qb, kb, vT, a, c);
    k_scores<<<dim3(16, 32, 2), dim3(256), 0, stream>>>(qb, kb, a, c, W2, b2, P, lpart);
    k_pv<<<dim3(8, 16, 4), dim3(256), 0, stream>>>(P, vT, lpart, ao);
    k_out<<<dim3(16, 32), dim3(256), 0, stream>>>(ao, WT + (size_t)3 * 512 * 512, bo, out);
}